// Round 10
// baseline (121.064 us; speedup 1.0000x reference)
//
#include <hip/hip_runtime.h>

// BaseModel_3100966387783 — per-variable masked 3-layer MLP, b=8192, D=128, h=64, o=2.
//
// R13: 2x2 wave-split -> sub-128-VGPR kernel with VOLUNTARY weight residency.
//   Evidence R6-R12: allocator lands at 116-120 VGPR in EVERY variant (the
//   4-waves/SIMD boundary is its soft goal) and re-fetches the 96-reg weight
//   set per iter from L2/LDS regardless of source-level structure; all seven
//   variants = 43-45 us. Fix: reshape work so the per-wave weight set is 48
//   regs (fits the allocator's own target):
//     wave (wi,wn), wi=w&1, wn=w>>1: owns i-half wi x batch-half wn.
//     L0: 32 MFMA (4nt x 2itl x 4ks), w0f[2][4] resident (32 regs).
//     h exchange via LDS bricks (nt,ks1=wi), barrier.
//     L1: 16 MFMA (4nt x 2itl2 x 2ks1), w1f[2][2] resident (16 regs).
//     finish: i2-half partials -> lq shfl-reduce -> LDS pbuf -> barrier ->
//             128 threads combine (+b2) -> one float2 store each.
//   x: 16 frags/iter direct from L2 (2x dup, 512 MB total < old 786 MB weight
//   stream). LDS 17.5 KB; grid (8,128)=1024 blocks -> 4 blocks/CU if VGPR<=128.
//   Prediction: VGPR 100-135, fused 44.5 -> 28-36 us, dur -> 90-100,
//   Occupancy 15 -> 22-30%. If flat 43-45 again: structure-independent floor.
//
// R12 (108.9): asm-pin compiled, VGPR 116, flat -> allocator wins any >128 fight.
// R9-R11: pre-read/pin attempts. R8: LDS weight stage (flat). R7: forced
// occupancy -> spill disaster. R3-R6: brick layout, ~43 us fused, VGPR 120.
//   brick = 1 KB = 64 lanes x 16 B bf16; lane l holds
//   T[tile*16 + (l&15)][ks*32 + (l>>4)*8 + 0..7] = one MFMA A/B fragment.

typedef __bf16 bf16_t;
typedef __bf16 bf16x8 __attribute__((ext_vector_type(8)));
typedef float  f32x4  __attribute__((ext_vector_type(4)));

#define LEAKY 0.01f

// ---------------- ws brick regions (byte offsets) ----------------
#define XB_OFF   0u                  // x bricks:   64 bt x 8 nt x 4 ks = 2048 bricks
#define W0B_OFF  (2048u*1024u)       // w0 masked: 128 t x 4 it x 4 ks = 2048
#define W1B_OFF  (4096u*1024u)       // w1:        128 t x 4 it x 2 ks = 1024
// total ws need: 5120 KiB (w2 read as fp32 directly in fused_mlp)

// =================== pre-kernel: fp32 -> bf16 brick-ify ===================
__global__ __launch_bounds__(256)
void brickify(const float* __restrict__ x,  const float* __restrict__ w0,
              const float* __restrict__ w1, unsigned char* __restrict__ ws)
{
    const int wid  = blockIdx.x * 4 + (threadIdx.x >> 6);  // one wave = one brick
    const int lane = threadIdx.x & 63;
    const int lr = lane & 15, lq = lane >> 4;

    float v[8];
    if (wid < 2048) {                        // ---- x bricks ----
        int bt = wid >> 5, rem = wid & 31, nt = rem >> 2, ks = rem & 3;
        const float* s = x + (size_t)(bt*128 + nt*16 + lr) * 128 + ks*32 + lq*8;
        const float4 a = *(const float4*)s, b = *(const float4*)(s + 4);
        v[0]=a.x; v[1]=a.y; v[2]=a.z; v[3]=a.w;
        v[4]=b.x; v[5]=b.y; v[6]=b.z; v[7]=b.w;
    } else if (wid < 4096) {                 // ---- w0 bricks (masked) ----
        int u = wid - 2048, t = u >> 4, rem = u & 15, it = rem >> 2, ks = rem & 3;
        int k0 = ks*32 + lq*8;
        const float* s = w0 + (size_t)(t*64 + it*16 + lr) * 128 + k0;
        const float4 a = *(const float4*)s, b = *(const float4*)(s + 4);
        v[0]=a.x; v[1]=a.y; v[2]=a.z; v[3]=a.w;
        v[4]=b.x; v[5]=b.y; v[6]=b.z; v[7]=b.w;
        #pragma unroll
        for (int j = 0; j < 8; ++j) if (k0 + j == t) v[j] = 0.f;
    } else {                                 // ---- w1 bricks ----
        int u = wid - 4096, t = u >> 3, rem = u & 7, it = rem >> 1, ks = rem & 1;
        const float* s = w1 + (size_t)(t*64 + it*16 + lr) * 64 + ks*32 + lq*8;
        const float4 a = *(const float4*)s, b = *(const float4*)(s + 4);
        v[0]=a.x; v[1]=a.y; v[2]=a.z; v[3]=a.w;
        v[4]=b.x; v[5]=b.y; v[6]=b.z; v[7]=b.w;
    }
    union { bf16_t h[8]; uint4 q; } pk;
    #pragma unroll
    for (int j = 0; j < 8; ++j) pk.h[j] = (bf16_t)v[j];
    ((uint4*)ws)[(size_t)wid * 64 + lane] = pk.q;   // dst = brick*1024 + lane*16
}

// =========================== main fused kernel ===========================
__global__ __launch_bounds__(256)
void fused_mlp(const unsigned char* __restrict__ ws,
               const float* __restrict__ w2,
               const float* __restrict__ b0, const float* __restrict__ b1,
               const float* __restrict__ b2, float* __restrict__ out)
{
    // hsm: 16 h bricks (nt 0..7, ks1 0..1), block-shared. pbuf: 2 x 128 float2.
    __shared__ __align__(16) unsigned char hsm[16384];
    __shared__ __align__(16) float2 pbuf[2][128];

    const int tid  = threadIdx.x;
    const int w    = tid >> 6;
    const int wi   = w & 1;            // i-half (hidden rows 32*wi..)
    const int wn   = w >> 1;           // batch-half (rows 64*wn..)
    const int lane = tid & 63;
    const int lr = lane & 15, lq = lane >> 4;
    const int g  = blockIdx.x;         // batch group: bt = g*8 + s
    const int t  = blockIdx.y;         // variable index

    // ---- resident weights: w0 slice (8 frags) + w1 slice (4 frags) ----
    bf16x8 w0f[2][4], w1f[2][2];
    {
        const unsigned char* w0p = ws + W0B_OFF + (size_t)t*16384 + lane*16;
        const unsigned char* w1p = ws + W1B_OFF + (size_t)t*8192  + lane*16;
        #pragma unroll
        for (int itl = 0; itl < 2; ++itl) {
            const int it = 2*wi + itl;
            #pragma unroll
            for (int ks = 0; ks < 4; ++ks)
                w0f[itl][ks] = *(const bf16x8*)(w0p + (it*4+ks)*1024);
            #pragma unroll
            for (int ks = 0; ks < 2; ++ks)
                w1f[itl][ks] = *(const bf16x8*)(w1p + (it*2+ks)*1024);
        }
    }

    // ---- w2 slice (this wave's i2-half), biases ----
    f32x4 w2q[2][2];                   // [o][itl2]
    f32x4 b0q[2], b1q[2];
    #pragma unroll
    for (int itl = 0; itl < 2; ++itl) {
        const int it = 2*wi + itl;
        b0q[itl] = *(const f32x4*)(b0 + t*64 + it*16 + lq*4);
        b1q[itl] = *(const f32x4*)(b1 + t*64 + it*16 + lq*4);
        #pragma unroll
        for (int o = 0; o < 2; ++o)
            w2q[o][itl] = *(const f32x4*)(w2 + t*128 + o*64 + it*16 + lq*4);
    }
    const float2 b2v = *(const float2*)(b2 + t*2);

    const unsigned char* xp = ws + XB_OFF + lane*16;

    for (int s = 0; s < 8; ++s) {
        const int bt = g*8 + s;

        // ---- x fragments for this wave's 4 nt tiles (16 x b128, L2-hit) ----
        bf16x8 xf[4][4];
        #pragma unroll
        for (int ntn = 0; ntn < 4; ++ntn) {
            const int nt = 4*wn + ntn;
            #pragma unroll
            for (int ks = 0; ks < 4; ++ks)
                xf[ntn][ks] = *(const bf16x8*)(xp + (size_t)(((bt*8 + nt)*4 + ks))*1024);
        }

        // ============ layer 0: i-half x batch-half (32 MFMA) ============
        f32x4 acc0[4][2];
        #pragma unroll
        for (int ntn = 0; ntn < 4; ++ntn)
            #pragma unroll
            for (int itl = 0; itl < 2; ++itl) acc0[ntn][itl] = b0q[itl];

        #pragma unroll
        for (int ks = 0; ks < 4; ++ks)
            #pragma unroll
            for (int itl = 0; itl < 2; ++itl)
                #pragma unroll
                for (int ntn = 0; ntn < 4; ++ntn)
                    acc0[ntn][itl] = __builtin_amdgcn_mfma_f32_16x16x32_bf16(
                                         w0f[itl][ks], xf[ntn][ks], acc0[ntn][itl], 0, 0, 0);

        // epi0 -> h bricks (nt, ks1=wi): i_loc = itl*16 + lq*4 + r
        #pragma unroll
        for (int ntn = 0; ntn < 4; ++ntn)
            #pragma unroll
            for (int itl = 0; itl < 2; ++itl) {
                union { bf16_t h[4]; unsigned long long u; } pk;
                #pragma unroll
                for (int r = 0; r < 4; ++r) {
                    float u = acc0[ntn][itl][r];
                    pk.h[r] = (bf16_t)fmaxf(u, LEAKY * u);
                }
                const int nt = 4*wn + ntn;
                int off = (nt*2 + wi)*1024
                        + ((itl*2 + (lq>>1))*16 + lr)*16 + (lq&1)*8;
                *(unsigned long long*)(hsm + off) = pk.u;
            }

        __syncthreads();   // B1: all h bricks written

        // ============ layer 1: i2-half x batch-half (16 MFMA) ============
        bf16x8 hf[4][2];
        #pragma unroll
        for (int ntn = 0; ntn < 4; ++ntn) {
            const int nt = 4*wn + ntn;
            #pragma unroll
            for (int ks1 = 0; ks1 < 2; ++ks1)
                hf[ntn][ks1] = *(const bf16x8*)(hsm + (nt*2 + ks1)*1024 + lane*16);
        }

        f32x4 acc1[4][2];
        #pragma unroll
        for (int ntn = 0; ntn < 4; ++ntn)
            #pragma unroll
            for (int itl = 0; itl < 2; ++itl) acc1[ntn][itl] = b1q[itl];

        #pragma unroll
        for (int ks1 = 0; ks1 < 2; ++ks1)
            #pragma unroll
            for (int itl = 0; itl < 2; ++itl)
                #pragma unroll
                for (int ntn = 0; ntn < 4; ++ntn)
                    acc1[ntn][itl] = __builtin_amdgcn_mfma_f32_16x16x32_bf16(
                                         w1f[itl][ks1], hf[ntn][ks1], acc1[ntn][itl], 0, 0, 0);

        // ---- finish: partial over this wave's i2-half, lq-reduce, pbuf ----
        #pragma unroll
        for (int ntn = 0; ntn < 4; ++ntn) {
            float p0 = 0.f, p1 = 0.f;
            #pragma unroll
            for (int itl = 0; itl < 2; ++itl)
                #pragma unroll
                for (int r = 0; r < 4; ++r) {
                    float u = acc1[ntn][itl][r];
                    float a = fmaxf(u, LEAKY * u);
                    p0 = fmaf(w2q[0][itl][r], a, p0);
                    p1 = fmaf(w2q[1][itl][r], a, p1);
                }
            p0 += __shfl_xor(p0, 16); p0 += __shfl_xor(p0, 32);
            p1 += __shfl_xor(p1, 16); p1 += __shfl_xor(p1, 32);
            if (lq == 0)
                pbuf[wi][(4*wn + ntn)*16 + lr] = (float2){p0, p1};
        }

        __syncthreads();   // B2: partials written (also fences h reads of this iter)

        // ---- combine + store: 128 threads, one float2 each ----
        if (tid < 128) {
            float2 a = pbuf[0][tid], b = pbuf[1][tid];
            float2 o2 = { a.x + b.x + b2v.x, a.y + b.y + b2v.y };
            *(float2*)(out + (size_t)(bt*128 + tid)*256 + t*2) = o2;
        }
        // next iter's h writes happen only after ALL waves pass B1(s+1)'s
        // predecessor region; pbuf reads above complete before any wave can
        // reach B1 of iter s+1, so single-buffered hsm/pbuf are race-free.
    }
}

extern "C" void kernel_launch(void* const* d_in, const int* in_sizes, int n_in,
                              void* d_out, int out_size, void* d_ws, size_t ws_size,
                              hipStream_t stream) {
    const float* x  = (const float*)d_in[0];
    const float* w0 = (const float*)d_in[1];
    const float* w1 = (const float*)d_in[2];
    const float* w2 = (const float*)d_in[3];
    const float* b0 = (const float*)d_in[4];
    const float* b1 = (const float*)d_in[5];
    const float* b2 = (const float*)d_in[6];
    unsigned char* ws = (unsigned char*)d_ws;   // needs 5120 KiB
    float* out = (float*)d_out;

    brickify<<<dim3(1280), dim3(256), 0, stream>>>(x, w0, w1, ws);
    // grid (8 groups, 128 t) = 1024 blocks; at VGPR<=128 & 17.5 KB LDS this
    // is 4 blocks/CU (16 waves/CU). XCD = blockid%8 = g: per-XCD working set
    // = one group's x (512 KB) + weights (3 MB) -> fits 4 MB L2.
    fused_mlp<<<dim3(8, 128), dim3(256), 0, stream>>>(ws, w2, b0, b1, b2, out);
}